// Round 1
// baseline (106.858 us; speedup 1.0000x reference)
//
#include <hip/hip_runtime.h>

// Problem constants
#define DIMM 128
#define NNODE 16
#define NBATCH 8
#define HDIM 4096

typedef unsigned short u16;
typedef __attribute__((ext_vector_type(8))) short short8;
typedef __attribute__((ext_vector_type(4))) float f32x4;

__device__ __forceinline__ u16 f2bf(float f) {
    unsigned u = __float_as_uint(f);
    return (u16)((u + 0x7FFFu + ((u >> 16) & 1u)) >> 16);  // RNE
}

// ---------------------------------------------------------------------------
// Build the 64 distinct MLP input rows (the reference's stack+reshape quirk):
// row r = i*4 + j  (i = node, j = batch-pair)
//   X[r][e] = nodes[2j + (e>=128)][i][e%128]
// ---------------------------------------------------------------------------
__global__ void k_build_x(const float* __restrict__ emb, u16* __restrict__ X) {
    int r = blockIdx.x, e = threadIdx.x;        // <<<64, 256>>>
    int i = r >> 2, j = r & 3;
    int b = 2 * j + (e >> 7), d = e & 127;
    X[r * 256 + e] = f2bf(emb[(b * NNODE + i) * DIMM + d]);
}

// ---------------------------------------------------------------------------
// Split-K GEMM: Cp[kidx][64][N] = A[64][k0:k0+kchunk] @ W[k0:k0+kchunk][N-tile]
// block = 256 threads (4 waves). Wave w: rows 16w..16w+15, cols c0..c0+31.
// W staged to LDS transposed [col][k] as bf16 so B-frags are ds_read_b128.
// A/B fragments use the same k-slot convention (8*(lane>>4)+i), which is
// correct for any hardware k-permutation since A and B share it.
// ---------------------------------------------------------------------------
__global__ __launch_bounds__(256) void k_gemm(
    const u16* __restrict__ A,   // [64][K] bf16 row-major
    const float* __restrict__ W, // [K][N] fp32 row-major
    float* __restrict__ Cp,      // [ksplit][64][N] fp32 partials
    int K, int N, int kchunk)
{
    __shared__ __align__(16) u16 Alds[64][136];  // [row][k] bf16, +8 pad
    __shared__ __align__(16) u16 Wlds[32][136];  // [col][k] bf16, +8 pad

    int tid = threadIdx.x;
    int wv = tid >> 6, lane = tid & 63;
    int c = lane & 15, g = lane >> 4;
    int c0 = blockIdx.x * 32;
    int k0 = blockIdx.y * kchunk;

    f32x4 acc0 = {0.f, 0.f, 0.f, 0.f};
    f32x4 acc1 = {0.f, 0.f, 0.f, 0.f};

    for (int kc = 0; kc < kchunk; kc += 128) {
        // --- stage A chunk [64][128] bf16: 64B per thread, coalesced 256B/row
        {
            int row = tid >> 2, seg = tid & 3;
            const uint4* src = reinterpret_cast<const uint4*>(A + (size_t)row * K + k0 + kc + seg * 32);
            uint4* dst = reinterpret_cast<uint4*>(&Alds[row][seg * 32]);
            dst[0] = src[0]; dst[1] = src[1]; dst[2] = src[2]; dst[3] = src[3];
        }
        // --- stage W chunk [128][32] fp32 -> transposed bf16 LDS [32][128]
        {
            int row = tid >> 1, half = tid & 1;   // row = k-local
            const float* src = W + (size_t)(k0 + kc + row) * N + c0 + half * 16;
            float4 p0 = ((const float4*)src)[0];
            float4 p1 = ((const float4*)src)[1];
            float4 p2 = ((const float4*)src)[2];
            float4 p3 = ((const float4*)src)[3];
            int cb = half * 16;
            Wlds[cb + 0][row] = f2bf(p0.x);  Wlds[cb + 1][row] = f2bf(p0.y);
            Wlds[cb + 2][row] = f2bf(p0.z);  Wlds[cb + 3][row] = f2bf(p0.w);
            Wlds[cb + 4][row] = f2bf(p1.x);  Wlds[cb + 5][row] = f2bf(p1.y);
            Wlds[cb + 6][row] = f2bf(p1.z);  Wlds[cb + 7][row] = f2bf(p1.w);
            Wlds[cb + 8][row] = f2bf(p2.x);  Wlds[cb + 9][row] = f2bf(p2.y);
            Wlds[cb + 10][row] = f2bf(p2.z); Wlds[cb + 11][row] = f2bf(p2.w);
            Wlds[cb + 12][row] = f2bf(p3.x); Wlds[cb + 13][row] = f2bf(p3.y);
            Wlds[cb + 14][row] = f2bf(p3.z); Wlds[cb + 15][row] = f2bf(p3.w);
        }
        __syncthreads();

        #pragma unroll
        for (int ks = 0; ks < 4; ++ks) {
            int kk = ks * 32 + g * 8;
            short8 a8 = *reinterpret_cast<const short8*>(&Alds[wv * 16 + c][kk]);
            short8 b0 = *reinterpret_cast<const short8*>(&Wlds[c][kk]);
            short8 b1 = *reinterpret_cast<const short8*>(&Wlds[16 + c][kk]);
            acc0 = __builtin_amdgcn_mfma_f32_16x16x32_bf16(a8, b0, acc0, 0, 0, 0);
            acc1 = __builtin_amdgcn_mfma_f32_16x16x32_bf16(a8, b1, acc1, 0, 0, 0);
        }
        __syncthreads();
    }

    // epilogue: D layout col = lane&15, row = 4*(lane>>4)+reg  [m89-verified]
    float* out = Cp + (size_t)blockIdx.y * 64 * N;
    int rbase = wv * 16 + g * 4;
    #pragma unroll
    for (int r = 0; r < 4; ++r) {
        out[(size_t)(rbase + r) * N + c0 + c]      = acc0[r];
        out[(size_t)(rbase + r) * N + c0 + 16 + c] = acc1[r];
    }
}

// ---------------------------------------------------------------------------
// Reduce split-K partials + bias + leaky_relu; mode 0 -> bf16 H, mode 1 ->
// sigmoid(leaky) fp32 (final pol).
// ---------------------------------------------------------------------------
__global__ void k_reduce(const float* __restrict__ Cp, const float* __restrict__ bias,
                         u16* __restrict__ Hb, float* __restrict__ Pf,
                         int N, int ksplit, int mode)
{
    int idx = blockIdx.x * 256 + threadIdx.x;
    if (idx >= 64 * N) return;
    int col = idx & (N - 1);          // N is a power of two (4096 / 256)
    float s = bias[col];
    for (int k = 0; k < ksplit; ++k) s += Cp[(size_t)k * 64 * N + idx];
    float a = (s >= 0.f) ? s : 0.01f * s;
    if (mode == 0) Hb[idx] = f2bf(a);
    else           Pf[idx] = 1.0f / (1.0f + __expf(-a));
}

// ---------------------------------------------------------------------------
// 50 power iterations for the 64 16x16 matrices + factored final reduction.
// 16 lanes per matrix, matrix row in registers. Normalization scale cancels
// in the output ratios, so rsqrtf precision is uncritical.
//   b<4 : out[b][n] = sum_s w[s*4+b][n]/w[s*4+b][s] * (sum_t Ts[b][s][t])
//   b>=4: out[b][n] = sum_t w[t*4+j][n] * (sum_s Ts[b][s][t]/w[t*4+j][s]), j=b-4
// ---------------------------------------------------------------------------
__global__ __launch_bounds__(1024) void k_power_out(
    const float* __restrict__ pol,  // [64][16][16]
    const float* __restrict__ Ts,   // [8][16][16]
    float* __restrict__ out)        // [8][16]
{
    __shared__ float w_lds[64][16];
    __shared__ float Ts_lds[2048];
    __shared__ float Cmat[8][16];

    int tid = threadIdx.x;
    int m = tid >> 4, r = tid & 15;
    int lane = tid & 63;
    int base = lane & 48;           // start lane of this matrix's 16-lane group

    float Mrow[16];
    #pragma unroll
    for (int q = 0; q < 4; ++q) {
        float4 v4 = reinterpret_cast<const float4*>(pol + m * 256 + r * 16)[q];
        Mrow[4 * q + 0] = v4.x; Mrow[4 * q + 1] = v4.y;
        Mrow[4 * q + 2] = v4.z; Mrow[4 * q + 3] = v4.w;
    }
    Ts_lds[tid] = Ts[tid];
    Ts_lds[tid + 1024] = Ts[tid + 1024];

    float v = 1.0f;                 // v0 = ones
    for (int it = 0; it < 50; ++it) {
        float wv = 0.f;
        #pragma unroll
        for (int cc = 0; cc < 16; ++cc)
            wv = fmaf(Mrow[cc], __shfl(v, base + cc, 64), wv);
        float s2 = wv * wv;
        s2 += __shfl_xor(s2, 1, 64);
        s2 += __shfl_xor(s2, 2, 64);
        s2 += __shfl_xor(s2, 4, 64);
        s2 += __shfl_xor(s2, 8, 64);
        v = wv * rsqrtf(s2);
    }
    w_lds[m][r] = v;
    __syncthreads();

    if (tid < 128) {
        int b = tid >> 4, x = tid & 15;
        float s = 0.f;
        if (b < 4) {                             // R[b][s=x] = sum_t Ts[b][x][t]
            const float* row = &Ts_lds[(b * 16 + x) * 16];
            #pragma unroll
            for (int t = 0; t < 16; ++t) s += row[t];
        } else {                                 // C[b][t=x]
            int j = b - 4;
            #pragma unroll
            for (int si = 0; si < 16; ++si)
                s += Ts_lds[(b * 16 + si) * 16 + x] / w_lds[x * 4 + j][si];
        }
        Cmat[b][x] = s;
    }
    __syncthreads();

    if (tid < 128) {
        int b = tid >> 4, n = tid & 15;
        float o = 0.f;
        if (b < 4) {
            #pragma unroll
            for (int si = 0; si < 16; ++si) {
                const float* wr = w_lds[si * 4 + b];
                o += wr[n] / wr[si] * Cmat[b][si];
            }
        } else {
            int j = b - 4;
            #pragma unroll
            for (int t = 0; t < 16; ++t)
                o += w_lds[t * 4 + j][n] * Cmat[b][t];
        }
        out[b * 16 + n] = o;
    }
}

// ---------------------------------------------------------------------------
extern "C" void kernel_launch(void* const* d_in, const int* in_sizes, int n_in,
                              void* d_out, int out_size, void* d_ws, size_t ws_size,
                              hipStream_t stream)
{
    const float* emb = (const float*)d_in[0];   // nodes_embeddings (8,16,128)
    const float* Ts  = (const float*)d_in[2];   // (8,16,16)
    const float* W1  = (const float*)d_in[3];  const float* b1 = (const float*)d_in[4];
    const float* W2  = (const float*)d_in[5];  const float* b2 = (const float*)d_in[6];
    const float* W3  = (const float*)d_in[7];  const float* b3 = (const float*)d_in[8];
    const float* W4  = (const float*)d_in[9];  const float* b4 = (const float*)d_in[10];
    float* outp = (float*)d_out;

    char* ws = (char*)d_ws;
    u16*   X   = (u16*)(ws + 0);              //  32 KB: X bf16 [64][256]
    u16*   Ha  = (u16*)(ws + 65536);          // 512 KB: H bf16 [64][4096]
    u16*   Hb2 = (u16*)(ws + 655360);         // 512 KB: H bf16 [64][4096]
    float* Cp  = (float*)(ws + 1245184);      //   4 MB: split-K partials
    float* pol = (float*)(ws + 5439488);      //  64 KB: pol fp32 [64][16][16]

    k_build_x<<<64, 256, 0, stream>>>(emb, X);

    // L1: X(64x256) @ W1(256x4096); ksplit=2, kchunk=128
    k_gemm<<<dim3(128, 2), 256, 0, stream>>>(X, W1, Cp, 256, 4096, 128);
    k_reduce<<<1024, 256, 0, stream>>>(Cp, b1, Ha, nullptr, 4096, 2, 0);

    // L2: H1 @ W2(4096x4096); ksplit=4, kchunk=1024
    k_gemm<<<dim3(128, 4), 256, 0, stream>>>(Ha, W2, Cp, 4096, 4096, 1024);
    k_reduce<<<1024, 256, 0, stream>>>(Cp, b2, Hb2, nullptr, 4096, 4, 0);

    // L3: H2 @ W3(4096x4096)
    k_gemm<<<dim3(128, 4), 256, 0, stream>>>(Hb2, W3, Cp, 4096, 4096, 1024);
    k_reduce<<<1024, 256, 0, stream>>>(Cp, b3, Ha, nullptr, 4096, 4, 0);

    // L4: H3 @ W4(4096x256); ksplit=32, kchunk=128
    k_gemm<<<dim3(8, 32), 256, 0, stream>>>(Ha, W4, Cp, 4096, 256, 128);
    k_reduce<<<64, 256, 0, stream>>>(Cp, b4, nullptr, pol, 256, 32, 1);

    // Power iteration + factored output reduction
    k_power_out<<<1, 1024, 0, stream>>>(pol, Ts, outp);

    (void)in_sizes; (void)n_in; (void)out_size; (void)ws_size;
}